// Round 1
// baseline (115.967 us; speedup 1.0000x reference)
//
#include <hip/hip_runtime.h>

// Problem constants (from reference):
//   B=16, C=256, H=W=16 -> L=256 tokens/batch, T=4096 tokens total
//   RATE_NUM=8 weight matrices of [C=256, R=256], bias [8,256], rate_choice[8]
// d_in: 0=x fp32[16,256,16,16], 1=indexes int32[4096], 2=weight fp32[8,256,256],
//       3=bias fp32[8,256], 4=rate_choice int32[8]
// d_out: fp32 [ x_masked[16,256,16,16] | mask[16,256,16,16] ]

__global__ __launch_bounds__(256) void rate_tok_kernel(
    const float* __restrict__ x, const int* __restrict__ indexes,
    const float* __restrict__ W, const float* __restrict__ bias,
    const int* __restrict__ rate, float* __restrict__ out) {
  const int t = blockIdx.x;      // token id in [0, 4096)
  const int b = t >> 8;          // batch
  const int l = t & 255;         // h*16+w
  const int r = threadIdx.x;     // output channel this thread produces

  __shared__ float xs[256];
  // stage x[b, :, l] into LDS (thread r loads channel c=r)
  xs[r] = x[(b << 16) + (r << 8) + l];

  const int g = indexes[t];      // which weight matrix
  const int rc = rate[g];        // active rate
  __syncthreads();

  // W[g][c][r]: stride 256 floats over c; lane r consecutive -> coalesced
  const float* w = W + (g << 16) + r;
  float acc = bias[(g << 8) + r];
#pragma unroll 8
  for (int c = 0; c < 256; ++c) {
    acc += xs[c] * w[c << 8];
  }

  const float m = (r < rc) ? 1.0f : 0.0f;
  const int o = (b << 16) + (r << 8) + l;  // out[b, r, l]
  out[o] = acc * m;
  out[(1 << 20) + o] = m;                  // mask output, same layout
}

extern "C" void kernel_launch(void* const* d_in, const int* in_sizes, int n_in,
                              void* d_out, int out_size, void* d_ws, size_t ws_size,
                              hipStream_t stream) {
  const float* x     = (const float*)d_in[0];
  const int*   idx   = (const int*)d_in[1];
  const float* W     = (const float*)d_in[2];
  const float* bias  = (const float*)d_in[3];
  const int*   rate  = (const int*)d_in[4];
  float* out = (float*)d_out;

  rate_tok_kernel<<<dim3(4096), dim3(256), 0, stream>>>(x, idx, W, bias, rate, out);
}

// Round 2
// 97.342 us; speedup vs baseline: 1.1913x; 1.1913x over previous
//
#include <hip/hip_runtime.h>

// B=16, C=256, L=256 (H*W), T=4096 tokens, G=8 groups, R=256
// d_in: 0=x fp32[16,256,16,16], 1=indexes int32[4096], 2=weight fp32[8,256,256],
//       3=bias fp32[8,256], 4=rate_choice int32[8]
// d_out: fp32 [ x_masked[16,256,16,16] | mask[16,256,16,16] ]
//
// Workspace layout:
//   counts  @ 0        : 8 int
//   bucket  @ 1024     : 8*4096 int  (128 KB)
//   xT      @ 262144   : 4096*256 fp32 (4 MB), token-major x
//   yT      @ 4456448  : 4096*256 fp32 (4 MB), token-major y (pre-mask)
#define WS_BUCKET 1024
#define WS_XT     262144
#define WS_YT     4456448
#define WS_NEED   8650752

// ---- bucket tokens by group (LDS-aggregated atomics; order within bucket is
//      nondeterministic but results are order-invariant) ----
__global__ __launch_bounds__(256) void bucket_kernel(const int* __restrict__ idx,
                                                     int* __restrict__ counts,
                                                     int* __restrict__ bucket) {
  __shared__ int lcount[8];
  __shared__ int lbase[8];
  const int tid = threadIdx.x;
  const int t = (blockIdx.x << 8) + tid;
  if (tid < 8) lcount[tid] = 0;
  __syncthreads();
  const int g = idx[t];
  const int lpos = atomicAdd(&lcount[g], 1);
  __syncthreads();
  if (tid < 8) lbase[tid] = atomicAdd(&counts[tid], lcount[tid]);
  __syncthreads();
  bucket[(g << 12) + lbase[g] + lpos] = t;
}

// ---- x [b][c][l] -> xT [b*256+l][c], coalesced both sides via LDS tile ----
__global__ __launch_bounds__(256) void xpose_kernel(const float* __restrict__ x,
                                                    float* __restrict__ xT) {
  __shared__ float tile[32][33];
  const int b = blockIdx.x;
  const int c0 = (blockIdx.y >> 3) << 5;
  const int l0 = (blockIdx.y & 7) << 5;
  const int j = threadIdx.x & 31;
  const int i = threadIdx.x >> 5;
#pragma unroll
  for (int ii = 0; ii < 4; ++ii) {
    const int c = c0 + (ii << 3) + i;
    tile[(ii << 3) + i][j] = x[(b << 16) + (c << 8) + l0 + j];
  }
  __syncthreads();
#pragma unroll
  for (int ii = 0; ii < 4; ++ii) {
    const int l = l0 + (ii << 3) + i;
    xT[(((b << 8) + l) << 8) + c0 + j] = tile[j][(ii << 3) + i];
  }
}

// ---- bucketed batch-matvec: block = (group g, chunk of 8 tokens) × 256 r ----
__global__ __launch_bounds__(256) void gemv_kernel(const float* __restrict__ xT,
                                                   const float* __restrict__ W,
                                                   const float* __restrict__ bias,
                                                   const int* __restrict__ counts,
                                                   const int* __restrict__ bucket,
                                                   float* __restrict__ yT) {
  const int g = blockIdx.x;
  const int n = counts[g];
  const int t0 = blockIdx.y << 3;
  if (t0 >= n) return;
  const int nt = min(8, n - t0);
  const int r = threadIdx.x;

  __shared__ float xs[8][256];
  __shared__ int toks[8];
  if (r < 8) toks[r] = (r < nt) ? bucket[(g << 12) + t0 + r] : bucket[(g << 12) + t0];
  __syncthreads();
#pragma unroll
  for (int t = 0; t < 8; ++t) xs[t][r] = xT[(toks[t] << 8) + r];  // coalesced; dups for t>=nt
  __syncthreads();

  float acc[8];
  const float brv = bias[(g << 8) + r];
#pragma unroll
  for (int t = 0; t < 8; ++t) acc[t] = brv;

  const float* w = W + (g << 16) + r;  // W[g][c][r], lane-contiguous in r
  for (int c4 = 0; c4 < 64; ++c4) {
    const float w0 = w[((c4 << 2) + 0) << 8];
    const float w1 = w[((c4 << 2) + 1) << 8];
    const float w2 = w[((c4 << 2) + 2) << 8];
    const float w3 = w[((c4 << 2) + 3) << 8];
#pragma unroll
    for (int t = 0; t < 8; ++t) {
      const float4 xv = *reinterpret_cast<const float4*>(&xs[t][c4 << 2]);  // LDS broadcast
      acc[t] += xv.x * w0 + xv.y * w1 + xv.z * w2 + xv.w * w3;
    }
  }

  for (int t = 0; t < nt; ++t) yT[(toks[t] << 8) + r] = acc[t];  // coalesced per token
}

// ---- yT [b*256+l][r] -> out [b][r][l] (*mask), plus mask output ----
__global__ __launch_bounds__(256) void out_kernel(const float* __restrict__ yT,
                                                  const int* __restrict__ idx,
                                                  const int* __restrict__ rate,
                                                  float* __restrict__ out) {
  __shared__ float tile[32][33];
  __shared__ int rcl[32];
  const int b = blockIdx.x;
  const int r0 = (blockIdx.y >> 3) << 5;
  const int l0 = (blockIdx.y & 7) << 5;
  const int j = threadIdx.x & 31;
  const int i = threadIdx.x >> 5;
#pragma unroll
  for (int ii = 0; ii < 4; ++ii) {
    const int l = l0 + (ii << 3) + i;
    tile[(ii << 3) + i][j] = yT[(((b << 8) + l) << 8) + r0 + j];
  }
  if (threadIdx.x < 32) rcl[threadIdx.x] = rate[idx[(b << 8) + l0 + threadIdx.x]];
  __syncthreads();
#pragma unroll
  for (int ii = 0; ii < 4; ++ii) {
    const int r = r0 + (ii << 3) + i;
    const float m = (r < rcl[j]) ? 1.0f : 0.0f;
    const int o = (b << 16) + (r << 8) + l0 + j;
    out[o] = tile[j][(ii << 3) + i] * m;
    out[(1 << 20) + o] = m;
  }
}

// ---- fallback (known-correct round-0 kernel) if ws too small ----
__global__ __launch_bounds__(256) void rate_tok_kernel(
    const float* __restrict__ x, const int* __restrict__ indexes,
    const float* __restrict__ W, const float* __restrict__ bias,
    const int* __restrict__ rate, float* __restrict__ out) {
  const int t = blockIdx.x;
  const int b = t >> 8;
  const int l = t & 255;
  const int r = threadIdx.x;
  __shared__ float xs[256];
  xs[r] = x[(b << 16) + (r << 8) + l];
  const int g = indexes[t];
  const int rc = rate[g];
  __syncthreads();
  const float* w = W + (g << 16) + r;
  float acc = bias[(g << 8) + r];
#pragma unroll 8
  for (int c = 0; c < 256; ++c) acc += xs[c] * w[c << 8];
  const float m = (r < rc) ? 1.0f : 0.0f;
  const int o = (b << 16) + (r << 8) + l;
  out[o] = acc * m;
  out[(1 << 20) + o] = m;
}

extern "C" void kernel_launch(void* const* d_in, const int* in_sizes, int n_in,
                              void* d_out, int out_size, void* d_ws, size_t ws_size,
                              hipStream_t stream) {
  const float* x    = (const float*)d_in[0];
  const int*   idx  = (const int*)d_in[1];
  const float* W    = (const float*)d_in[2];
  const float* bias = (const float*)d_in[3];
  const int*   rate = (const int*)d_in[4];
  float* out = (float*)d_out;

  if (ws_size >= (size_t)WS_NEED) {
    int*   counts = (int*)d_ws;
    int*   bucket = (int*)((char*)d_ws + WS_BUCKET);
    float* xT     = (float*)((char*)d_ws + WS_XT);
    float* yT     = (float*)((char*)d_ws + WS_YT);
    hipMemsetAsync(counts, 0, 8 * sizeof(int), stream);
    bucket_kernel<<<dim3(16), dim3(256), 0, stream>>>(idx, counts, bucket);
    xpose_kernel<<<dim3(16, 64), dim3(256), 0, stream>>>(x, xT);
    gemv_kernel<<<dim3(8, 512), dim3(256), 0, stream>>>(xT, W, bias, counts, bucket, yT);
    out_kernel<<<dim3(16, 64), dim3(256), 0, stream>>>(yT, idx, rate, out);
  } else {
    rate_tok_kernel<<<dim3(4096), dim3(256), 0, stream>>>(x, idx, W, bias, rate, out);
  }
}